// Round 4
// baseline (305.506 us; speedup 1.0000x reference)
//
#include <hip/hip_runtime.h>
#include <hip/hip_bf16.h>
#include <cstdint>

#define TSEQ 4096
#define CDIM 2048
#define HDIM 128

typedef short bf8v __attribute__((ext_vector_type(8)));  // 8 bf16 raw bits (4 VGPRs)
typedef float f4v  __attribute__((ext_vector_type(4)));

__device__ __forceinline__ unsigned short f2b(float f) {
  union { float f; unsigned u; } v; v.f = f;
  unsigned u = v.u;
  return (unsigned short)((u + 0x7fffu + ((u >> 16) & 1u)) >> 16);  // RNE
}

__device__ __forceinline__ unsigned cvtpk(float a, float b) {
  unsigned r;
  asm("v_cvt_pk_bf16_f32 %0, %1, %2" : "=v"(r) : "v"(a), "v"(b));
  return r;  // lo = bf16(a), hi = bf16(b), RNE
}

__device__ __forceinline__ f4v mfma16(bf8v a, bf8v b, f4v c) {
  return __builtin_amdgcn_mfma_f32_16x16x32_bf16(a, b, c, 0, 0, 0);
}

__device__ __forceinline__ void gload_lds16(const void* g, void* l) {
  __builtin_amdgcn_global_load_lds(
      (const __attribute__((address_space(1))) unsigned int*)g,
      (__attribute__((address_space(3))) unsigned int*)l, 16, 0, 0);
}

// ---------------- Kernel 1: Wq|Wk|Wv fp32 -> Wcat bf16 in B-FRAGMENT order -------
// (round-2 harness-verified) Chunk c = ((nb*64 + kkg)*64 + lane), 8 bf16 each:
// value[e] = W[nb*16 + (lane&15)][kkg*32 + (lane>>4)*8 + e]. proj loads these 16B
// chunks directly as MFMA B-operand fragments (Wcat = 1.5 MB, L2-resident).
__global__ void wcat_kernel(const float* __restrict__ Wq, const float* __restrict__ Wk,
                            const float* __restrict__ Wv, unsigned short* __restrict__ Wcat) {
  int c = blockIdx.x * 256 + threadIdx.x;   // 98304 chunks total
  int lane = c & 63;
  int kkg  = (c >> 6) & 63;
  int nb   = c >> 12;                        // 0..23
  int n  = nb * 16 + (lane & 15);
  int k0 = kkg * 32 + (lane >> 4) * 8;
  const float* src;
  if (n < 128)      src = Wq + (size_t)n * CDIM + k0;
  else if (n < 256) src = Wk + (size_t)(n - 128) * CDIM + k0;
  else              src = Wv + (size_t)(n - 256) * CDIM + k0;
  float4 f0 = ((const float4*)src)[0];
  float4 f1 = ((const float4*)src)[1];
  bf8v o;
  o[0] = (short)f2b(f0.x); o[1] = (short)f2b(f0.y);
  o[2] = (short)f2b(f0.z); o[3] = (short)f2b(f0.w);
  o[4] = (short)f2b(f1.x); o[5] = (short)f2b(f1.y);
  o[6] = (short)f2b(f1.z); o[7] = (short)f2b(f1.w);
  *(bf8v*)(Wcat + (size_t)c * 8) = o;
}

// ---------------- Kernel 2: proj GEMM v7 — counted-vmcnt pipeline ----------------
// Grid (256,3), 256 thr / 4 waves, wave tile 32x64 (acc[2][4]): 4 ds_read : 8 MFMA.
// A: fp32 via global_load_lds into 3-deep LDS ring (24 KB), XOR-granule swizzle
//    (slot s of row r holds source granule s^(r&7); read granule g at s=g^(r&7)
//    -> 2-way banks, free). Converted in-register via v_cvt_pk_bf16_f32.
// B: register fragments direct from fragment-ordered Wcat (coalesced L2 hits),
//    depth-1 prefetch. NO ds_write anywhere in the loop.
// Sync: s_waitcnt vmcnt(6) + raw s_barrier per iter — 6 VMEM ops (A(t+1) x2 +
// B(t) x4 at wait point) stay in flight across every barrier; never drains to 0.
__global__ __launch_bounds__(256, 4) void proj_gemm(const float* __restrict__ A,
                                                    const unsigned short* __restrict__ Bw,
                                                    unsigned short* __restrict__ QB,
                                                    unsigned short* __restrict__ KA,
                                                    unsigned short* __restrict__ VB) {
  __shared__ union {
    float As[3][64][32];         // 24 KB: 3-deep ring, rows = A rows, 32 k-floats
    unsigned short Ct[64][132];  // 16.9 KB, epilogue only
  } sm;
  const int m0 = blockIdx.x * 64;
  const int y  = blockIdx.y;          // 0=q, 1=k, 2=v
  const int tid = threadIdx.x;
  const int lane = tid & 63;
  const int w = tid >> 6;             // 4 waves
  const int wm = (w & 1) * 32;        // row strip
  const int wn = (w >> 1) * 64;       // col strip (within the 128-col y-panel)
  const int llo = lane & 15, lhi = lane >> 4;

  f4v acc[2][4];
#pragma unroll
  for (int i = 0; i < 2; ++i)
#pragma unroll
    for (int j = 0; j < 4; ++j) acc[i][j] = (f4v){0.f, 0.f, 0.f, 0.f};

  // ---- A staging (gload_lds): wave w stages rows w*16 .. w*16+15 ----
  // lane -> row +(lane>>3), slot lane&7 holds source granule (lane&7)^(lane>>3)
  const int ar8 = lane >> 3;
  const int agr = (lane & 7) ^ ar8;
  const float* aptr = A + (size_t)(m0 + w * 16 + ar8) * CDIM + agr * 4;
  auto stageA = [&](int it, int buf) {
#pragma unroll
    for (int q = 0; q < 2; ++q)
      gload_lds16(aptr + (size_t)q * 8 * CDIM + it * 32, &sm.As[buf][w * 16 + q * 8][0]);
  };

  // ---- B fragment loads (fragment-ordered Wcat) ----
  // frag j of k-group it: chunk (( (y*8 + (w>>1)*4 + j)*64 + it )*64 + lane)
  const unsigned short* bptr =
      Bw + (size_t)(y * 8 + (w >> 1) * 4) * 64 * 512 + (size_t)lane * 8;
  auto loadB = [&](bf8v* dst, int it) {
#pragma unroll
    for (int j = 0; j < 4; ++j)
      dst[j] = *(const bf8v*)(bptr + (size_t)(j * 64 + it) * 512);
  };

  // ---- prologue: A tiles 0,1 into bufs 0,1; B frags for tile 0 ----
  stageA(0, 0);
  stageA(1, 1);
  bf8v bcur[4];
  loadB(bcur, 0);

  int rb = 0;  // ring buffer holding tile 'it'
  for (int it = 0; it < 64; ++it) {
    asm volatile("s_waitcnt vmcnt(6)" ::: "memory");
    __builtin_amdgcn_s_barrier();
    __builtin_amdgcn_sched_barrier(0);
    if (it < 62) {
      int wb = rb + 2; if (wb >= 3) wb -= 3;
      stageA(it + 2, wb);
    }
    bf8v bnxt[4];
    if (it < 63) loadB(bnxt, it + 1);
    // compute tile it from As[rb] + bcur
    bf8v af[2];
#pragma unroll
    for (int i = 0; i < 2; ++i) {
      const float* ab = &sm.As[rb][wm + i * 16 + llo][0];
      float4 f0 = *(const float4*)(ab + (((lhi << 1) | 0) ^ (llo & 7)) * 4);
      float4 f1 = *(const float4*)(ab + (((lhi << 1) | 1) ^ (llo & 7)) * 4);
      union { bf8v v; unsigned u[4]; } o;
      o.u[0] = cvtpk(f0.x, f0.y); o.u[1] = cvtpk(f0.z, f0.w);
      o.u[2] = cvtpk(f1.x, f1.y); o.u[3] = cvtpk(f1.z, f1.w);
      af[i] = o.v;
    }
#pragma unroll
    for (int i = 0; i < 2; ++i)
#pragma unroll
      for (int j = 0; j < 4; ++j) acc[i][j] = mfma16(af[i], bcur[j], acc[i][j]);
#pragma unroll
    for (int j = 0; j < 4; ++j) bcur[j] = bnxt[j];
    rb = (rb == 2) ? 0 : rb + 1;
  }

  // ---- epilogue: stage 64x128 C tile in LDS, then emit the verified layouts ----
  __syncthreads();
#pragma unroll
  for (int i = 0; i < 2; ++i)
#pragma unroll
    for (int j = 0; j < 4; ++j)
#pragma unroll
      for (int r = 0; r < 4; ++r)
        sm.Ct[wm + i * 16 + lhi * 4 + r][wn + j * 16 + llo] = f2b(acc[i][j][r]);
  __syncthreads();
  if (y < 2) {
    unsigned short* dst = (y == 0) ? QB : KA;
    const size_t base16 = (size_t)(m0 >> 4);
#pragma unroll
    for (int p = 0; p < 4; ++p) {
      int g = p * 256 + tid;
      int t16l = g >> 8, kk = (g >> 6) & 3, ln = g & 63;
      int lo = ln & 15, hi = ln >> 4;
      bf8v v = *(const bf8v*)&sm.Ct[t16l * 16 + lo][kk * 32 + hi * 8];
      *(bf8v*)(dst + (((base16 + t16l) * 4 + kk) * 64 + ln) * 8) = v;
    }
  } else {
    const size_t base32 = (size_t)(m0 >> 5);
#pragma unroll
    for (int p = 0; p < 5; ++p) {
      int g = p * 256 + tid;
      if (g < 1152) {
        int jbl = g / 576;
        int ht  = (g % 576) >> 6;
        int ln  = g & 63;
        int lo = ln & 15, hi = ln >> 4;
        bf8v v;
        if (ht == 8) {
#pragma unroll
          for (int e = 0; e < 8; ++e) v[e] = (lo == 0) ? (short)0x3F80 : (short)0;
        } else {
#pragma unroll
          for (int e = 0; e < 8; ++e) v[e] = (short)sm.Ct[jbl * 32 + hi * 8 + e][ht * 16 + lo];
        }
        *(bf8v*)(VB + (((base32 + jbl) * 9 + ht) * 512 + (size_t)ln * 8)) = v;
      }
    }
  }
}

// ---------------- Kernel 3: flash attention v6 — software-pipelined, no spills -----
// (unchanged)
__global__ __launch_bounds__(256, 4) void attn6(const unsigned short* __restrict__ QB,
                                                const unsigned short* __restrict__ KA,
                                                const unsigned short* __restrict__ VB,
                                                float* __restrict__ out) {
  __shared__ union SM {
    unsigned short Ps[4][2][16][68];                      // [wave][buf][row][col] 17.4 KB
    struct { float Om[4][16][68]; float Lm[4][16]; } mg;  // 17.7 KB
  } sm;
  const int x = blockIdx.x;
  const int b = x & 3;
  const int u = x >> 2;
  const int g = u >> 6, r0 = u & 63;
  const int s = (g & 1) ? (g * 64 + 63 - r0) : (g * 64 + r0);
  const int lastjt = s >> 2;
  const int tid = threadIdx.x;
  const int w = tid >> 6, lane = tid & 63;
  const int llo = lane & 15, lhi = lane >> 4;
  const float scale = 0.022097086912079608f;  // 2048^-0.5

  bf8v aK[4];
  {
    const unsigned short* kp = KA + (size_t)(b * 256 + s) * 2048;
#pragma unroll
    for (int kk = 0; kk < 4; ++kk) aK[kk] = *(const bf8v*)(kp + (kk * 64 + lane) * 8);
  }

  f4v Oacc[9];
#pragma unroll
  for (int nt = 0; nt < 9; ++nt) Oacc[nt] = (f4v){0.f, 0.f, 0.f, 0.f};

  auto computeS = [&](int jtS, int buf) {
    const unsigned short* qp = QB + (size_t)(b * 256 + jtS * 4) * 2048;
#pragma unroll
    for (int ct = 0; ct < 4; ++ct) {
      f4v acc = (f4v){0.f, 0.f, 0.f, 0.f};
#pragma unroll
      for (int kk = 0; kk < 4; ++kk) {
        bf8v bq = *(const bf8v*)(qp + ((ct * 4 + kk) * 64 + lane) * 8);
        acc = mfma16(aK[kk], bq, acc);
      }
#pragma unroll
      for (int r = 0; r < 4; ++r) {
        float sv = acc[r];
        if (jtS == lastjt) {
          int j = jtS * 64 + ct * 16 + llo;
          int i = s * 16 + lhi * 4 + r;
          if (j > i) sv = -3.0e38f;
        }
        sm.Ps[w][buf][lhi * 4 + r][ct * 16 + llo] = f2b(__expf(sv * scale));
      }
    }
  };

  if (w <= lastjt) computeS(w, 0);
  int buf = 0;
  for (int jt = w; jt <= lastjt; jt += 4) {
    bf8v aP0 = *(const bf8v*)&sm.Ps[w][buf][llo][lhi * 8];
    bf8v aP1 = *(const bf8v*)&sm.Ps[w][buf][llo][32 + lhi * 8];
    if (jt + 4 <= lastjt) computeS(jt + 4, buf ^ 1);
    const unsigned short* vp = VB + (size_t)(b * 128 + jt * 2) * 4608;  // 9 ht * 512
#pragma unroll
    for (int nt = 0; nt < 9; ++nt) {
      f4v o = Oacc[nt];
      o = mfma16(aP0, *(const bf8v*)(vp + nt * 512 + (size_t)lane * 8), o);
      o = mfma16(aP1, *(const bf8v*)(vp + 4608 + nt * 512 + (size_t)lane * 8), o);
      Oacc[nt] = o;
    }
    buf ^= 1;
  }

#pragma unroll
  for (int half = 0; half < 2; ++half) {
    __syncthreads();
#pragma unroll
    for (int nt = 0; nt < 4; ++nt)
#pragma unroll
      for (int r = 0; r < 4; ++r)
        sm.mg.Om[w][lhi * 4 + r][nt * 16 + llo] = Oacc[half * 4 + nt][r];
    if (half == 0 && llo == 0) {
#pragma unroll
      for (int r = 0; r < 4; ++r) sm.mg.Lm[w][lhi * 4 + r] = Oacc[8][r];
    }
    __syncthreads();
    {
      int row = tid >> 4, c0 = (tid & 15) * 4;
      float L = sm.mg.Lm[0][row] + sm.mg.Lm[1][row] + sm.mg.Lm[2][row] + sm.mg.Lm[3][row];
      float inv = 1.0f / L;
      float* op = out + (size_t)(b * TSEQ + s * 16 + row) * HDIM + half * 64 + c0;
#pragma unroll
      for (int e = 0; e < 4; ++e) {
        float o = sm.mg.Om[0][row][c0 + e] + sm.mg.Om[1][row][c0 + e] +
                  sm.mg.Om[2][row][c0 + e] + sm.mg.Om[3][row][c0 + e];
        op[e] = o * inv;
      }
    }
  }
}

extern "C" void kernel_launch(void* const* d_in, const int* in_sizes, int n_in,
                              void* d_out, int out_size, void* d_ws, size_t ws_size,
                              hipStream_t stream) {
  const float* idx = (const float*)d_in[0];
  const float* Wq  = (const float*)d_in[1];
  const float* Wk  = (const float*)d_in[2];
  const float* Wv  = (const float*)d_in[3];
  float* out = (float*)d_out;
  char* ws = (char*)d_ws;
  unsigned short* Wcat = (unsigned short*)ws;                        // 1.57 MB
  unsigned short* QB   = (unsigned short*)(ws + ((size_t)2  << 20)); // 4.2 MB
  unsigned short* KA   = (unsigned short*)(ws + ((size_t)7  << 20)); // 4.2 MB
  unsigned short* VB   = (unsigned short*)(ws + ((size_t)12 << 20)); // 4.72 MB

  wcat_kernel<<<384, 256, 0, stream>>>(Wq, Wk, Wv, Wcat);
  proj_gemm<<<dim3(256, 3), 256, 0, stream>>>(idx, Wcat, QB, KA, VB);
  attn6<<<1024, 256, 0, stream>>>(QB, KA, VB, out);
}

// Round 5
// 300.891 us; speedup vs baseline: 1.0153x; 1.0153x over previous
//
#include <hip/hip_runtime.h>
#include <hip/hip_bf16.h>
#include <cstdint>

#define TSEQ 4096
#define CDIM 2048
#define HDIM 128

typedef short bf8v __attribute__((ext_vector_type(8)));  // 8 bf16 raw bits (4 VGPRs)
typedef float f4v  __attribute__((ext_vector_type(4)));

__device__ __forceinline__ unsigned short f2b(float f) {
  union { float f; unsigned u; } v; v.f = f;
  unsigned u = v.u;
  return (unsigned short)((u + 0x7fffu + ((u >> 16) & 1u)) >> 16);  // RNE
}

__device__ __forceinline__ unsigned cvtpk(float a, float b) {
  unsigned r;
  asm("v_cvt_pk_bf16_f32 %0, %1, %2" : "=v"(r) : "v"(a), "v"(b));
  return r;  // lo16 = bf16(a), hi16 = bf16(b), RNE — same values as f2b pair
}

__device__ __forceinline__ f4v mfma16(bf8v a, bf8v b, f4v c) {
  return __builtin_amdgcn_mfma_f32_16x16x32_bf16(a, b, c, 0, 0, 0);
}

__device__ __forceinline__ void gload_lds16(const void* g, void* l) {
  __builtin_amdgcn_global_load_lds(
      (const __attribute__((address_space(1))) unsigned int*)g,
      (__attribute__((address_space(3))) unsigned int*)l, 16, 0, 0);
}

// ---------------- Kernel 1: Wq|Wk|Wv fp32 -> Wcat bf16 [384][2048] (row-major) ----
__global__ void wcat_kernel(const float* __restrict__ Wq, const float* __restrict__ Wk,
                            const float* __restrict__ Wv, unsigned short* __restrict__ Wcat) {
  int e = (blockIdx.x * 256 + threadIdx.x) * 4;
  int n = e >> 11;
  int k = e & 2047;
  const float* src;
  if (n < 128)      src = Wq + (size_t)n * CDIM + k;
  else if (n < 256) src = Wk + (size_t)(n - 128) * CDIM + k;
  else              src = Wv + (size_t)(n - 256) * CDIM + k;
  float4 f = *(const float4*)src;
  ushort4 o;
  o.x = f2b(f.x); o.y = f2b(f.y); o.z = f2b(f.z); o.w = f2b(f.w);
  *(ushort4*)(Wcat + e) = o;
}

// ---------------- Kernel 2: proj GEMM v6 (verified) + cvtpk A-staging ------------
// Structure identical to round-3 v6 (grid (256,3), 64x128 block, 8 waves 32x32,
// BK=64, gload_lds B with XOR-granule swizzle, 50.4 KB LDS -> 3 blk/CU).
// Only change: A fp32->bf16 staging uses v_cvt_pk_bf16_f32 (1 instr per 2 floats)
// instead of scalar f2b (~4 instrs per float) — cuts the serialized VALU phase.
__global__ __launch_bounds__(512, 6) void proj_gemm(const float* __restrict__ A,
                                                    const unsigned short* __restrict__ Bw,
                                                    unsigned short* __restrict__ QB,
                                                    unsigned short* __restrict__ KA,
                                                    unsigned short* __restrict__ VB) {
  __shared__ union {
    struct { unsigned short As[2][64][72]; unsigned short Bs[2][128][64]; } st;  // 50.4 KB
    unsigned short Ct[64][132];                                                  // 16.9 KB
  } sm;
  const int m0 = blockIdx.x * 64;
  const int y  = blockIdx.y;          // 0=q, 1=k, 2=v
  const int n0g = y * 128;
  const int tid = threadIdx.x;
  const int lane = tid & 63;
  const int w = tid >> 6;
  const int wm = (w & 1) * 32, wn = (w >> 1) * 32;
  const int llo = lane & 15, lhi = lane >> 4;

  f4v acc[2][2];
#pragma unroll
  for (int i = 0; i < 2; ++i)
#pragma unroll
    for (int j = 0; j < 2; ++j) acc[i][j] = (f4v){0.f, 0.f, 0.f, 0.f};

  // A staging: 2 float4 per thread (64x64 fp32 = 1024 granules / 512 thr)
  const int ar0 = tid >> 4;           // 0..31
  const int ac0 = (tid & 15) * 4;     // 0..60
  const float* aptr0 = A + (size_t)(m0 + ar0) * CDIM + ac0;
  const float* aptr1 = A + (size_t)(m0 + 32 + ar0) * CDIM + ac0;

  // B staging: 2 gload_lds per wave (16 rows of 64 bf16 = 128 granules).
  const int brow = lane >> 3;
  const int bgs  = (lane & 7) ^ brow;
  const unsigned short* bptr = Bw + (size_t)(n0g + w * 16 + brow) * CDIM + bgs * 8;

  // ---- prologue: stage K-tile 0 into buf 0 ----
  float4 fa0 = *(const float4*)(aptr0);
  float4 fa1 = *(const float4*)(aptr1);
  gload_lds16(bptr,            &sm.st.Bs[0][w * 16][0]);
  gload_lds16(bptr + 8 * CDIM, &sm.st.Bs[0][w * 16 + 8][0]);
  {
    uint2 p0, p1;
    p0.x = cvtpk(fa0.x, fa0.y); p0.y = cvtpk(fa0.z, fa0.w);
    p1.x = cvtpk(fa1.x, fa1.y); p1.y = cvtpk(fa1.z, fa1.w);
    *(uint2*)&sm.st.As[0][ar0][ac0]      = p0;
    *(uint2*)&sm.st.As[0][32 + ar0][ac0] = p1;
  }

  for (int it = 0; it < 32; ++it) {
    const int cur = it & 1;
    __syncthreads();
    if (it < 31) {
      fa0 = *(const float4*)(aptr0 + (it + 1) * 64);
      fa1 = *(const float4*)(aptr1 + (it + 1) * 64);
      const int nxt = cur ^ 1;
      gload_lds16(bptr + (it + 1) * 64,            &sm.st.Bs[nxt][w * 16][0]);
      gload_lds16(bptr + 8 * CDIM + (it + 1) * 64, &sm.st.Bs[nxt][w * 16 + 8][0]);
    }
#pragma unroll
    for (int kk = 0; kk < 2; ++kk) {
      bf8v af[2], bfr[2];
      af[0] = *(const bf8v*)&sm.st.As[cur][wm + llo][kk * 32 + lhi * 8];
      af[1] = *(const bf8v*)&sm.st.As[cur][wm + 16 + llo][kk * 32 + lhi * 8];
      const int bofs = (((kk << 2) + lhi) ^ (llo & 7)) * 8;
      bfr[0] = *(const bf8v*)&sm.st.Bs[cur][wn + llo][bofs];
      bfr[1] = *(const bf8v*)&sm.st.Bs[cur][wn + 16 + llo][bofs];
#pragma unroll
      for (int i = 0; i < 2; ++i)
#pragma unroll
        for (int j = 0; j < 2; ++j) acc[i][j] = mfma16(af[i], bfr[j], acc[i][j]);
    }
    if (it < 31) {
      const int nxt = cur ^ 1;
      uint2 p0, p1;
      p0.x = cvtpk(fa0.x, fa0.y); p0.y = cvtpk(fa0.z, fa0.w);
      p1.x = cvtpk(fa1.x, fa1.y); p1.y = cvtpk(fa1.z, fa1.w);
      *(uint2*)&sm.st.As[nxt][ar0][ac0]      = p0;
      *(uint2*)&sm.st.As[nxt][32 + ar0][ac0] = p1;
    }
  }
  __syncthreads();
#pragma unroll
  for (int i = 0; i < 2; ++i)
#pragma unroll
    for (int j = 0; j < 2; ++j)
#pragma unroll
      for (int r = 0; r < 4; ++r)
        sm.Ct[wm + i * 16 + lhi * 4 + r][wn + j * 16 + llo] = f2b(acc[i][j][r]);
  __syncthreads();
  if (y < 2) {
    unsigned short* dst = (y == 0) ? QB : KA;
    const size_t base16 = (size_t)(m0 >> 4);
#pragma unroll
    for (int p = 0; p < 2; ++p) {
      int g = p * 512 + tid;
      int t16l = g >> 8, kk = (g >> 6) & 3, ln = g & 63;
      int lo = ln & 15, hi = ln >> 4;
      bf8v v = *(const bf8v*)&sm.Ct[t16l * 16 + lo][kk * 32 + hi * 8];
      *(bf8v*)(dst + (((base16 + t16l) * 4 + kk) * 64 + ln) * 8) = v;
    }
  } else {
    const size_t base32 = (size_t)(m0 >> 5);
#pragma unroll
    for (int p = 0; p < 3; ++p) {
      int g = p * 512 + tid;
      if (g < 1152) {
        int jbl = g / 576;
        int ht  = (g % 576) >> 6;
        int ln  = g & 63;
        int lo = ln & 15, hi = ln >> 4;
        bf8v v;
        if (ht == 8) {
#pragma unroll
          for (int e = 0; e < 8; ++e) v[e] = (lo == 0) ? (short)0x3F80 : (short)0;
        } else {
#pragma unroll
          for (int e = 0; e < 8; ++e) v[e] = (short)sm.Ct[jbl * 32 + hi * 8 + e][ht * 16 + lo];
        }
        *(bf8v*)(VB + (((base32 + jbl) * 9 + ht) * 512 + (size_t)ln * 8)) = v;
      }
    }
  }
}

// ---------------- Kernel 3: flash attention v7 — two 16-row strips per block -----
// Each block owns strips sA=2u, sB=2u+1 (same lastjt = u>>1, proven: (2u)>>2 ==
// (2u+1)>>2 == u>>1). Every Q fragment and V fragment load is SHARED between the
// two strips' MFMA chains -> Q/V L2 traffic halved vs attn6; MFMA total unchanged.
// Per-strip math (mask, P layout, PV, merge) is attn6-verbatim, instantiated
// twice with static indexing (array-ref lambda params — no runtime reg indexing).
// Balanced pairing: u = t<64 ? 2t : 255-2t makes co-resident (x, x+256) work sums
// constant. 256 thr / 4 waves, (256,2) -> 256 VGPR cap (est ~180, no spill).
__global__ __launch_bounds__(256, 2) void attn7(const unsigned short* __restrict__ QB,
                                                const unsigned short* __restrict__ KA,
                                                const unsigned short* __restrict__ VB,
                                                float* __restrict__ out) {
  __shared__ union SM {
    unsigned short Ps[2][4][2][16][68];                   // [strip][wave][buf][row][col] 34.8 KB
    struct { float Om[4][16][68]; float Lm[4][16]; } mg;  // 17.7 KB
  } sm;
  const int x = blockIdx.x;          // 512 blocks
  const int b = x & 3;
  const int t = x >> 2;              // 0..127
  const int u = (t < 64) ? (2 * t) : (255 - 2 * t);  // balanced: u(t)+u(t+64)=127
  const int sA = u * 2;              // strip A (16 rows), strip B = sA+1
  const int lastjt = u >> 1;
  const int tid = threadIdx.x;
  const int w = tid >> 6, lane = tid & 63;
  const int llo = lane & 15, lhi = lane >> 4;
  const float scale = 0.022097086912079608f;  // 2048^-0.5

  bf8v aKA[4], aKB[4];
  {
    const unsigned short* kp = KA + (size_t)(b * 256 + sA) * 2048;
#pragma unroll
    for (int kk = 0; kk < 4; ++kk) {
      aKA[kk] = *(const bf8v*)(kp + (kk * 64 + lane) * 8);
      aKB[kk] = *(const bf8v*)(kp + 2048 + (kk * 64 + lane) * 8);
    }
  }

  f4v OA[9], OB[9];
#pragma unroll
  for (int nt = 0; nt < 9; ++nt) {
    OA[nt] = (f4v){0.f, 0.f, 0.f, 0.f};
    OB[nt] = (f4v){0.f, 0.f, 0.f, 0.f};
  }

  // S = K.Q^T for BOTH strips sharing each Q fragment load; exp -> P LDS bufs
  auto computeS2 = [&](int jtS, int buf) {
    const unsigned short* qp = QB + (size_t)(b * 256 + jtS * 4) * 2048;
#pragma unroll
    for (int ct = 0; ct < 4; ++ct) {
      f4v accA = (f4v){0.f, 0.f, 0.f, 0.f};
      f4v accB = (f4v){0.f, 0.f, 0.f, 0.f};
#pragma unroll
      for (int kk = 0; kk < 4; ++kk) {
        bf8v bq = *(const bf8v*)(qp + ((ct * 4 + kk) * 64 + lane) * 8);
        accA = mfma16(aKA[kk], bq, accA);
        accB = mfma16(aKB[kk], bq, accB);
      }
#pragma unroll
      for (int r = 0; r < 4; ++r) {
        float svA = accA[r], svB = accB[r];
        if (jtS == lastjt) {
          int j  = jtS * 64 + ct * 16 + llo;
          int iA = sA * 16 + lhi * 4 + r;
          if (j > iA)      svA = -3.0e38f;
          if (j > iA + 16) svB = -3.0e38f;   // strip B rows = strip A rows + 16
        }
        sm.Ps[0][w][buf][lhi * 4 + r][ct * 16 + llo] = f2b(__expf(svA * scale));
        sm.Ps[1][w][buf][lhi * 4 + r][ct * 16 + llo] = f2b(__expf(svB * scale));
      }
    }
  };

  if (w <= lastjt) computeS2(w, 0);
  int buf = 0;
  for (int jt = w; jt <= lastjt; jt += 4) {
    bf8v aP0A = *(const bf8v*)&sm.Ps[0][w][buf][llo][lhi * 8];
    bf8v aP1A = *(const bf8v*)&sm.Ps[0][w][buf][llo][32 + lhi * 8];
    bf8v aP0B = *(const bf8v*)&sm.Ps[1][w][buf][llo][lhi * 8];
    bf8v aP1B = *(const bf8v*)&sm.Ps[1][w][buf][llo][32 + lhi * 8];
    if (jt + 4 <= lastjt) computeS2(jt + 4, buf ^ 1);
    const unsigned short* vp = VB + (size_t)(b * 128 + jt * 2) * 4608;  // 9 ht * 512
#pragma unroll
    for (int nt = 0; nt < 9; ++nt) {
      bf8v v0 = *(const bf8v*)(vp + nt * 512 + (size_t)lane * 8);
      bf8v v1 = *(const bf8v*)(vp + 4608 + nt * 512 + (size_t)lane * 8);
      f4v oa = OA[nt];
      oa = mfma16(aP0A, v0, oa);
      oa = mfma16(aP1A, v1, oa);
      OA[nt] = oa;
      f4v ob = OB[nt];
      ob = mfma16(aP0B, v0, ob);
      ob = mfma16(aP1B, v1, ob);
      OB[nt] = ob;
    }
    buf ^= 1;
  }

  // merge the 4 waves' partials per strip (attn6-verbatim, twice)
  auto mergeOne = [&](const f4v (&O)[9], int sX) {
#pragma unroll
    for (int half = 0; half < 2; ++half) {
      __syncthreads();
#pragma unroll
      for (int nt = 0; nt < 4; ++nt)
#pragma unroll
        for (int r = 0; r < 4; ++r)
          sm.mg.Om[w][lhi * 4 + r][nt * 16 + llo] = O[half * 4 + nt][r];
      if (half == 0 && llo == 0) {
#pragma unroll
        for (int r = 0; r < 4; ++r) sm.mg.Lm[w][lhi * 4 + r] = O[8][r];
      }
      __syncthreads();
      {
        int row = tid >> 4, c0 = (tid & 15) * 4;
        float L = sm.mg.Lm[0][row] + sm.mg.Lm[1][row] + sm.mg.Lm[2][row] + sm.mg.Lm[3][row];
        float inv = 1.0f / L;
        float* op = out + (size_t)(b * TSEQ + sX * 16 + row) * HDIM + half * 64 + c0;
#pragma unroll
        for (int e = 0; e < 4; ++e) {
          float o = sm.mg.Om[0][row][c0 + e] + sm.mg.Om[1][row][c0 + e] +
                    sm.mg.Om[2][row][c0 + e] + sm.mg.Om[3][row][c0 + e];
          op[e] = o * inv;
        }
      }
    }
  };
  mergeOne(OA, sA);
  mergeOne(OB, sA + 1);
}

extern "C" void kernel_launch(void* const* d_in, const int* in_sizes, int n_in,
                              void* d_out, int out_size, void* d_ws, size_t ws_size,
                              hipStream_t stream) {
  const float* idx = (const float*)d_in[0];
  const float* Wq  = (const float*)d_in[1];
  const float* Wk  = (const float*)d_in[2];
  const float* Wv  = (const float*)d_in[3];
  float* out = (float*)d_out;
  char* ws = (char*)d_ws;
  unsigned short* Wcat = (unsigned short*)ws;                        // 1.57 MB
  unsigned short* QB   = (unsigned short*)(ws + ((size_t)2  << 20)); // 4.2 MB
  unsigned short* KA   = (unsigned short*)(ws + ((size_t)7  << 20)); // 4.2 MB
  unsigned short* VB   = (unsigned short*)(ws + ((size_t)12 << 20)); // 4.72 MB

  wcat_kernel<<<768, 256, 0, stream>>>(Wq, Wk, Wv, Wcat);
  proj_gemm<<<dim3(256, 3), 512, 0, stream>>>(idx, Wcat, QB, KA, VB);
  attn7<<<512, 256, 0, stream>>>(QB, KA, VB, out);
}